// Round 3
// baseline (211.169 us; speedup 1.0000x reference)
//
#include <hip/hip_runtime.h>
#include <stdint.h>

// ---------------- constants ----------------
constexpr int IMG     = 3072;
constexpr int PH      = 384;              // patch height/width
constexpr int NPATCH  = 64;
constexpr int NSLICE  = 8;                // slices per patch (48 rows each)
constexpr int SROWS   = PH / NSLICE;      // 48
constexpr int WPR     = IMG / 32;         // 96 words per row
constexpr uint32_t KEY_LO = 0x3F000000u;  // bits(0.5f)
// Exact fp32 bit-step of +-5e-5f for th in [0.5,1): 839 ulps per step (no RNE ties)
constexpr uint32_t STEPU = 839u;
// Threshold lattice: {bits(0.85f) + k*839}. bits(0.85f)-KEY_LO = 5872026 = 6998*839+704
// -> lattice origin within [0.5,1) is G0 = KEY_LO + 704.
constexpr uint32_t G0 = KEY_LO + 704u;
// Lattice bins: idx = ceil((key - G0)/839) for key > G0; idx in [1, 9998].
// count(key > g_j) = sum of bins >= j+1. bin 0 (keys <= G0) never counted.
constexpr int NB = 9999;                  // bins 0..9998
constexpr int NPAIR    = 5000;            // u32 bin-pairs per slice row (bin 9999 = pad 0)
constexpr int PRSTRIDE = 10000;           // u16 elements per slice row (even -> u32 aligned)
constexpr int CH = (NB + 255) / 256;      // 40 bins per thread in scan

// binclose tiling: 24 out rows x 48 out words per block -> 128*2 = 256 blocks
constexpr int TR = 24;
constexpr int TC = 48;
constexpr int GR = IMG / TR;              // 128
constexpr int GC = WPR / TC;              // 2
constexpr int BROWS  = TR + 8;            // 32 binary rows  [y0-4, y0+TR+4)
constexpr int BWORDS = TC + 4;            // 52 binary words [w0-2, w0+TC+2)
constexpr int DROWS  = TR + 4;            // 28 dilated rows [y0-2, y0+TR+2)
constexpr int DWORDS = TC + 2;            // 50 dilated words[w0-1, w0+TC+1)

// ---------------- workspace layout (bytes) ----------------
constexpr size_t OFF_THS  = 0;                                   // 64 f32
constexpr size_t OFF_DONE = 256;                                 // 64 u32 (memset 0)
constexpr size_t OFF_PRIV = 512;                                 // 512*PRSTRIDE u16 = 10.24 MB

// ---------------- K1: lattice histogram (u16 private) + fused per-patch scan --
// 512 blocks = 64 patches x 8 slices. Each block histograms its slice in LDS and
// stores a pair-packed u16 row. The 8th finisher per patch (elected via
// device-scope atomicAdd + threadfence, rocPRIM decoupled-lookback pattern)
// re-reads the 8 L3-hot rows and computes the patch threshold in-place.
//
// th(p) = g_j, j = (smallest i in [1,9998] with S(i) <= C_hi) - 1, where
// S(i) = sum of bins >= i (so count(key > g_j) = S(j+1)).
// Equivalence with the reference chain (carried th1): since C_lo > C_hi, both
// while-loops always terminate at the first lattice point with frac <= hi,
// independent of the carried start. C_hi reproduces fp32 mean/compare semantics.
__global__ __launch_bounds__(256) void k_hist(const float* __restrict__ x,
                                              uint16_t* __restrict__ priv,
                                              uint32_t* __restrict__ done,
                                              float* __restrict__ ths) {
    __shared__ uint32_t hist[NB + 1];     // bin 9999 = pad (stays 0)
    __shared__ uint32_t csum[256];
    __shared__ uint32_t after[256];
    __shared__ int best_s[256];
    __shared__ int elect_s;
    const int p = blockIdx.x >> 3, s = blockIdx.x & 7;
    const int t = threadIdx.x;
    const int pr = p >> 3, pc = p & 7;
    const float* base = x + (size_t)(pr * PH + s * SROWS) * IMG + pc * PH;

    for (int i = t; i < NB + 1; i += 256) hist[i] = 0;
    __syncthreads();

    constexpr int NF4 = SROWS * (PH / 4);  // 48*96 = 4608
    for (int i = t; i < NF4; i += 256) {
        int r = i / 96, c = i - r * 96;
        float4 v = *reinterpret_cast<const float4*>(base + (size_t)r * IMG + c * 4);
        float vals[4] = {v.x, v.y, v.z, v.w};
#pragma unroll
        for (int k = 0; k < 4; ++k) {
            uint32_t key = __float_as_uint(vals[k]);
            if (key > G0) {                                   // bin 0 never counted
                uint32_t idx = (key - KEY_LO + 134u) / 839u;  // = ceil((key-G0)/839)
                if (idx > (uint32_t)(NB - 1)) idx = NB - 1;   // safety (keys >= 1.0)
                atomicAdd(&hist[idx], 1u);
            }
        }
    }
    __syncthreads();

    // pair-packed u16 store (per-slice bin max = 18432 < 65536)
    uint32_t* out = reinterpret_cast<uint32_t*>(priv + (size_t)blockIdx.x * PRSTRIDE);
    for (int i = t; i < NPAIR; i += 256)
        out[i] = (hist[2 * i] & 0xFFFFu) | (hist[2 * i + 1] << 16);

    // ---- election: last slice of the patch performs the scan ----
    __syncthreads();
    __threadfence();                      // release priv stores (device scope)
    __syncthreads();
    if (t == 0) {
        uint32_t old = atomicAdd(&done[p], 1u);
        elect_s = (old == NSLICE - 1);
    }
    __syncthreads();
    if (!elect_s) return;
    __threadfence();                      // acquire before reading siblings' rows

    // sum 8 slice rows into hist[] (reuse LDS)
    {
        const uint32_t* rows[NSLICE];
#pragma unroll
        for (int b = 0; b < NSLICE; ++b)
            rows[b] = reinterpret_cast<const uint32_t*>(priv + (size_t)(p * NSLICE + b) * PRSTRIDE);
        for (int i = t; i < NPAIR; i += 256) {
            uint32_t lo = 0, hi = 0;
#pragma unroll
            for (int b = 0; b < NSLICE; ++b) {
                uint32_t v = rows[b][i];
                lo += v & 0xFFFFu;
                hi += v >> 16;
            }
            hist[2 * i]     = lo;
            hist[2 * i + 1] = hi;
        }
    }
    __syncthreads();

    const int lo_i = t * CH;
    const int hi_i = (lo_i + CH < NB) ? lo_i + CH : NB;
    {
        uint32_t sum = 0;
        for (int i = lo_i; i < hi_i; ++i) sum += hist[i];
        csum[t] = sum;
    }
    __syncthreads();
    if (t == 0) {
        uint32_t acc = 0;
        for (int u = 255; u >= 0; --u) { after[u] = acc; acc += csum[u]; }
    }
    __syncthreads();

    // C_hi: largest c with (float)c/147456.0f <= hi_tgt (fp32 mean semantics)
    const bool frame = (pr == 0 || pr == 7 || pc == 0 || pc == 7);
    const float hi_t = 0.08f - (frame ? 0.05f : 0.0f);
    int d = (int)((double)hi_t * 147456.0);
    while ((float)(d + 1) / 147456.0f <= hi_t) ++d;
    while (d > 0 && (float)d / 147456.0f > hi_t) --d;
    const uint32_t Chi = (uint32_t)d;

    // walk own chunk top-down; S(i) grows as i decreases; valid set {S(i)<=Chi}
    // is an upper range, so the last valid i seen is the chunk-local minimum.
    {
        uint32_t run = after[t];
        int best = 0x7FFFFFFF;
        for (int i = hi_i - 1; i >= lo_i; --i) {
            run += hist[i];                // run = S(i)
            if (i >= 1 && run <= Chi) best = i;
        }
        best_s[t] = best;
    }
    __syncthreads();
    for (int st = 128; st > 0; st >>= 1) {
        if (t < st) { int o = best_s[t + st]; if (o < best_s[t]) best_s[t] = o; }
        __syncthreads();
    }
    if (t == 0) {
        int istar = best_s[0];
        int j = (istar == 0x7FFFFFFF) ? (NB - 2) : (istar - 1);  // clamp: unreachable
        ths[p] = __uint_as_float(G0 + (uint32_t)j * STEPU);
    }
}

// ---------------- K2: fused binarize + 5x5 close + f32 store ------------------
__device__ __forceinline__ uint32_t hshift5_or(uint32_t c, uint32_t l, uint32_t r) {
    uint64_t xr = ((uint64_t)r << 32) | c;
    uint64_t xl = ((uint64_t)c << 32) | l;
    return c | (uint32_t)(xr >> 1) | (uint32_t)(xr >> 2)
             | (uint32_t)(xl >> 31) | (uint32_t)(xl >> 30);
}
__device__ __forceinline__ uint32_t hshift5_and(uint32_t c, uint32_t l, uint32_t r) {
    uint64_t xr = ((uint64_t)r << 32) | c;
    uint64_t xl = ((uint64_t)c << 32) | l;
    return c & (uint32_t)(xr >> 1) & (uint32_t)(xr >> 2)
             & (uint32_t)(xl >> 31) & (uint32_t)(xl >> 30);
}

__global__ __launch_bounds__(256) void k_binclose(const float* __restrict__ x,
                                                  const float* __restrict__ ths,
                                                  float* __restrict__ out) {
    __shared__ float    ths_s[NPATCH];
    __shared__ uint32_t Bs[BROWS][BWORDS];   // binarized halo tile (zero-pad OOB)
    __shared__ uint32_t Ds[DROWS][DWORDS];   // dilated tile
    const int bid = blockIdx.x;
    const int ry = bid / GC, cx = bid - ry * GC;
    const int y0 = ry * TR;                  // first output row
    const int w0 = cx * TC;                  // first output word
    const int t = threadIdx.x;

    if (t < NPATCH) ths_s[t] = ths[t];
    __syncthreads();

    // binarize x -> bits.  Bs[r][w] <-> global row y0-4+r, global word w0-2+w.
    for (int i = t; i < BROWS * BWORDS; i += 256) {
        int r = i / BWORDS, w = i - r * BWORDS;
        int gy = y0 - 4 + r;
        int gw = w0 - 2 + w;
        uint32_t m = 0;
        if (gy >= 0 && gy < IMG && gw >= 0 && gw < WPR) {
            float th = ths_s[(gy / PH) * 8 + gw / 12];   // gw*32/384 = gw/12
            const float* row = x + (size_t)gy * IMG + gw * 32;
#pragma unroll
            for (int k = 0; k < 8; ++k) {
                float4 v = *reinterpret_cast<const float4*>(row + 4 * k);
                m |= (uint32_t)(v.x > th) << (4 * k + 0);
                m |= (uint32_t)(v.y > th) << (4 * k + 1);
                m |= (uint32_t)(v.z > th) << (4 * k + 2);
                m |= (uint32_t)(v.w > th) << (4 * k + 3);
            }
        }
        Bs[r][w] = m;
    }
    __syncthreads();

    // dilate: Ds[rd][wd] <-> global row y0-2+rd, global word w0-1+wd
    for (int i = t; i < DROWS * DWORDS; i += 256) {
        int rd = i / DWORDS, wd = i - rd * DWORDS;
        uint32_t acc = 0;
#pragma unroll
        for (int dy = -2; dy <= 2; ++dy) {
            int rb = rd + 2 + dy;            // Bs row for the same global row + dy
            uint32_t cc = Bs[rb][wd + 1];
            uint32_t ll = Bs[rb][wd];        // global word-1 (OOB words are 0)
            uint32_t rr = Bs[rb][wd + 2];
            acc |= hshift5_or(cc, ll, rr);
        }
        Ds[rd][wd] = acc;
    }
    __syncthreads();

    // erode rows [y0, y0+TR) (OOB rows contribute 1s -> skip) + f32 store
    for (int i = t; i < TR * TC; i += 256) {
        int r = i / TC, w = i - r * TC;
        int gy = y0 + r;
        int gw = w0 + w;
        uint32_t acc = 0xFFFFFFFFu;
#pragma unroll
        for (int dy = -2; dy <= 2; ++dy) {
            int yy = gy + dy;
            if (yy < 0 || yy >= IMG) continue;
            int rd = r + 2 + dy;             // Ds row for global row yy
            uint32_t cc = Ds[rd][w + 1];
            uint32_t ll = (gw > 0)       ? Ds[rd][w]     : 0xFFFFFFFFu;
            uint32_t rr = (gw < WPR - 1) ? Ds[rd][w + 2] : 0xFFFFFFFFu;
            acc &= hshift5_and(cc, ll, rr);
        }
        float* o = out + (size_t)gy * IMG + gw * 32;
#pragma unroll
        for (int k = 0; k < 8; ++k) {
            float4 v;
            v.x = (acc & (1u << (4 * k + 0))) ? 1.0f : 0.0f;
            v.y = (acc & (1u << (4 * k + 1))) ? 1.0f : 0.0f;
            v.z = (acc & (1u << (4 * k + 2))) ? 1.0f : 0.0f;
            v.w = (acc & (1u << (4 * k + 3))) ? 1.0f : 0.0f;
            *reinterpret_cast<float4*>(o + 4 * k) = v;
        }
    }
}

extern "C" void kernel_launch(void* const* d_in, const int* in_sizes, int n_in,
                              void* d_out, int out_size, void* d_ws, size_t ws_size,
                              hipStream_t stream) {
    const float* x = (const float*)d_in[0];
    float* out = (float*)d_out;
    uint8_t* ws = (uint8_t*)d_ws;

    float*    ths  = (float*)(ws + OFF_THS);
    uint32_t* done = (uint32_t*)(ws + OFF_DONE);
    uint16_t* priv = (uint16_t*)(ws + OFF_PRIV);

    hipMemsetAsync(done, 0, NPATCH * sizeof(uint32_t), stream);
    k_hist    <<<NPATCH * NSLICE, 256, 0, stream>>>(x, priv, done, ths);
    k_binclose<<<GR * GC,         256, 0, stream>>>(x, ths, out);
}

// Round 4
// 132.248 us; speedup vs baseline: 1.5968x; 1.5968x over previous
//
#include <hip/hip_runtime.h>
#include <stdint.h>

// ---------------- constants ----------------
constexpr int IMG     = 3072;
constexpr int PH      = 384;              // patch height/width
constexpr int NPATCH  = 64;
constexpr int NSLICE  = 8;                // slices per patch (48 rows each)
constexpr int SROWS   = PH / NSLICE;      // 48
constexpr int WPR     = IMG / 32;         // 96 words per row
constexpr uint32_t KEY_LO = 0x3F000000u;  // bits(0.5f)
// Exact fp32 bit-step of +-5e-5f for th in [0.5,1): 839 ulps per step (no RNE ties)
constexpr uint32_t STEPU = 839u;
// Threshold lattice: {bits(0.85f) + k*839}. bits(0.85f)-KEY_LO = 5872026 = 6998*839+704
// -> lattice origin within [0.5,1) is G0 = KEY_LO + 704.
constexpr uint32_t G0 = KEY_LO + 704u;
// Lattice bins: idx = ceil((key - G0)/839) for key > G0; idx in [1, 9998].
// count(key > g_j) = sum of bins >= j+1. bin 0 (keys <= G0) never counted.
constexpr int NB = 9999;                  // bins 0..9998
constexpr int NPAIR    = 5000;            // u32 bin-pairs per slice row (bin 9999 = pad 0)
constexpr int PRSTRIDE = 10000;           // u16 elements per slice row (even -> u32 aligned)
constexpr int CH = (NB + 255) / 256;      // 40 bins per thread in scan

// binclose tiling: 24 out rows x 48 out words per block -> 128*2 = 256 blocks
constexpr int TR = 24;
constexpr int TC = 48;
constexpr int GR = IMG / TR;              // 128
constexpr int GC = WPR / TC;              // 2
constexpr int BROWS  = TR + 8;            // 32 binary rows  [y0-4, y0+TR+4)
constexpr int BWORDS = TC + 4;            // 52 binary words [w0-2, w0+TC+2)
constexpr int DROWS  = TR + 4;            // 28 dilated rows [y0-2, y0+TR+2)
constexpr int DWORDS = TC + 2;            // 50 dilated words[w0-1, w0+TC+1)

// ---------------- workspace layout (bytes) ----------------
constexpr size_t OFF_THS  = 0;                                   // 64 f32
constexpr size_t OFF_PRIV = 512;                                 // 512*PRSTRIDE u16 = 10.24 MB

// ---------------- K1: lattice histogram -> u16 pair-packed private row --------
// 512 blocks = 64 patches x 8 slices of 48 rows. LDS 9999-bin histogram written
// to a private slot -> full overwrite, no zero kernel, no global atomics, no
// fences (R3 lesson: device-scope fences = per-XCD L2 writeback+invalidate,
// catastrophic in-kernel; cross-block dataflow goes through dispatch boundary).
__global__ __launch_bounds__(256) void k_hist(const float* __restrict__ x,
                                              uint16_t* __restrict__ priv) {
    __shared__ uint32_t hist[NB + 1];     // bin 9999 = pad (stays 0)
    const int p = blockIdx.x >> 3, s = blockIdx.x & 7;
    const int t = threadIdx.x;
    const int pr = p >> 3, pc = p & 7;
    const float* base = x + (size_t)(pr * PH + s * SROWS) * IMG + pc * PH;

    for (int i = t; i < NB + 1; i += 256) hist[i] = 0;
    __syncthreads();

    constexpr int NF4 = SROWS * (PH / 4);  // 48*96 = 4608
    for (int i = t; i < NF4; i += 256) {
        int r = i / 96, c = i - r * 96;
        float4 v = *reinterpret_cast<const float4*>(base + (size_t)r * IMG + c * 4);
        float vals[4] = {v.x, v.y, v.z, v.w};
#pragma unroll
        for (int k = 0; k < 4; ++k) {
            uint32_t key = __float_as_uint(vals[k]);
            if (key > G0) {                                   // bin 0 never counted
                uint32_t idx = (key - KEY_LO + 134u) / 839u;  // = ceil((key-G0)/839)
                if (idx > (uint32_t)(NB - 1)) idx = NB - 1;   // safety (keys >= 1.0)
                atomicAdd(&hist[idx], 1u);
            }
        }
    }
    __syncthreads();

    // pair-packed u16 store (per-slice bin max = 18432 < 65536)
    uint32_t* out = reinterpret_cast<uint32_t*>(priv + (size_t)blockIdx.x * PRSTRIDE);
    for (int i = t; i < NPAIR; i += 256)
        out[i] = (hist[2 * i] & 0xFFFFu) | (hist[2 * i + 1] << 16);
}

// ---------------- K2: slice-sum + per-patch suffix scan -> threshold ----------
// th(p) = g_j, j = (smallest i in [1,9998] with S(i) <= C_hi) - 1, where
// S(i) = sum of bins >= i (so count(key > g_j) = S(j+1)).
// Equivalence with the reference chain (carried th1): since C_lo > C_hi, both
// while-loops always terminate at the first lattice point with frac <= hi,
// independent of the carried start. C_hi reproduces fp32 mean/compare semantics.
__global__ __launch_bounds__(256) void k_scan(const uint16_t* __restrict__ priv,
                                              float* __restrict__ ths) {
    __shared__ uint32_t h[NB + 1];
    __shared__ uint32_t csum[256];
    __shared__ uint32_t after[256];
    __shared__ int best_s[256];
    const int p = blockIdx.x, t = threadIdx.x;

    // sum 8 pair-packed slice rows
    for (int i = t; i < NPAIR; i += 256) {
        uint32_t lo = 0, hi = 0;
#pragma unroll
        for (int b = 0; b < NSLICE; ++b) {
            uint32_t v = reinterpret_cast<const uint32_t*>(
                priv + (size_t)(p * NSLICE + b) * PRSTRIDE)[i];
            lo += v & 0xFFFFu;
            hi += v >> 16;
        }
        h[2 * i]     = lo;
        h[2 * i + 1] = hi;
    }
    __syncthreads();

    const int lo_i = t * CH;
    const int hi_i = (lo_i + CH < NB) ? lo_i + CH : NB;
    {
        uint32_t sum = 0;
        for (int i = lo_i; i < hi_i; ++i) sum += h[i];
        csum[t] = sum;
    }
    __syncthreads();
    if (t == 0) {
        uint32_t acc = 0;
        for (int u = 255; u >= 0; --u) { after[u] = acc; acc += csum[u]; }
    }
    __syncthreads();

    // C_hi: largest c with (float)c/147456.0f <= hi_tgt (fp32 mean semantics)
    const int pr = p >> 3, pc = p & 7;
    const bool frame = (pr == 0 || pr == 7 || pc == 0 || pc == 7);
    const float hi_t = 0.08f - (frame ? 0.05f : 0.0f);
    int d = (int)((double)hi_t * 147456.0);
    while ((float)(d + 1) / 147456.0f <= hi_t) ++d;
    while (d > 0 && (float)d / 147456.0f > hi_t) --d;
    const uint32_t Chi = (uint32_t)d;

    // walk own chunk top-down; S(i) grows as i decreases; valid set {S(i)<=Chi}
    // is an upper range, so the last valid i seen is the chunk-local minimum.
    {
        uint32_t run = after[t];
        int best = 0x7FFFFFFF;
        for (int i = hi_i - 1; i >= lo_i; --i) {
            run += h[i];                   // run = S(i)
            if (i >= 1 && run <= Chi) best = i;
        }
        best_s[t] = best;
    }
    __syncthreads();
    for (int st = 128; st > 0; st >>= 1) {
        if (t < st) { int o = best_s[t + st]; if (o < best_s[t]) best_s[t] = o; }
        __syncthreads();
    }
    if (t == 0) {
        int istar = best_s[0];
        int j = (istar == 0x7FFFFFFF) ? (NB - 2) : (istar - 1);  // clamp: unreachable
        ths[p] = __uint_as_float(G0 + (uint32_t)j * STEPU);
    }
}

// ---------------- K3: fused binarize + 5x5 close + f32 store ------------------
__device__ __forceinline__ uint32_t hshift5_or(uint32_t c, uint32_t l, uint32_t r) {
    uint64_t xr = ((uint64_t)r << 32) | c;
    uint64_t xl = ((uint64_t)c << 32) | l;
    return c | (uint32_t)(xr >> 1) | (uint32_t)(xr >> 2)
             | (uint32_t)(xl >> 31) | (uint32_t)(xl >> 30);
}
__device__ __forceinline__ uint32_t hshift5_and(uint32_t c, uint32_t l, uint32_t r) {
    uint64_t xr = ((uint64_t)r << 32) | c;
    uint64_t xl = ((uint64_t)c << 32) | l;
    return c & (uint32_t)(xr >> 1) & (uint32_t)(xr >> 2)
             & (uint32_t)(xl >> 31) & (uint32_t)(xl >> 30);
}

__global__ __launch_bounds__(256) void k_binclose(const float* __restrict__ x,
                                                  const float* __restrict__ ths,
                                                  float* __restrict__ out) {
    __shared__ float    ths_s[NPATCH];
    __shared__ uint32_t Bs[BROWS][BWORDS];   // binarized halo tile (zero-pad OOB)
    __shared__ uint32_t Ds[DROWS][DWORDS];   // dilated tile
    const int bid = blockIdx.x;
    const int ry = bid / GC, cx = bid - ry * GC;
    const int y0 = ry * TR;                  // first output row
    const int w0 = cx * TC;                  // first output word
    const int t = threadIdx.x;

    if (t < NPATCH) ths_s[t] = ths[t];
    __syncthreads();

    // binarize x -> bits.  Bs[r][w] <-> global row y0-4+r, global word w0-2+w.
    for (int i = t; i < BROWS * BWORDS; i += 256) {
        int r = i / BWORDS, w = i - r * BWORDS;
        int gy = y0 - 4 + r;
        int gw = w0 - 2 + w;
        uint32_t m = 0;
        if (gy >= 0 && gy < IMG && gw >= 0 && gw < WPR) {
            float th = ths_s[(gy / PH) * 8 + gw / 12];   // gw*32/384 = gw/12
            const float* row = x + (size_t)gy * IMG + gw * 32;
#pragma unroll
            for (int k = 0; k < 8; ++k) {
                float4 v = *reinterpret_cast<const float4*>(row + 4 * k);
                m |= (uint32_t)(v.x > th) << (4 * k + 0);
                m |= (uint32_t)(v.y > th) << (4 * k + 1);
                m |= (uint32_t)(v.z > th) << (4 * k + 2);
                m |= (uint32_t)(v.w > th) << (4 * k + 3);
            }
        }
        Bs[r][w] = m;
    }
    __syncthreads();

    // dilate: Ds[rd][wd] <-> global row y0-2+rd, global word w0-1+wd
    for (int i = t; i < DROWS * DWORDS; i += 256) {
        int rd = i / DWORDS, wd = i - rd * DWORDS;
        uint32_t acc = 0;
#pragma unroll
        for (int dy = -2; dy <= 2; ++dy) {
            int rb = rd + 2 + dy;            // Bs row for the same global row + dy
            uint32_t cc = Bs[rb][wd + 1];
            uint32_t ll = Bs[rb][wd];        // global word-1 (OOB words are 0)
            uint32_t rr = Bs[rb][wd + 2];
            acc |= hshift5_or(cc, ll, rr);
        }
        Ds[rd][wd] = acc;
    }
    __syncthreads();

    // erode rows [y0, y0+TR) (OOB rows contribute 1s -> skip) + f32 store
    for (int i = t; i < TR * TC; i += 256) {
        int r = i / TC, w = i - r * TC;
        int gy = y0 + r;
        int gw = w0 + w;
        uint32_t acc = 0xFFFFFFFFu;
#pragma unroll
        for (int dy = -2; dy <= 2; ++dy) {
            int yy = gy + dy;
            if (yy < 0 || yy >= IMG) continue;
            int rd = r + 2 + dy;             // Ds row for global row yy
            uint32_t cc = Ds[rd][w + 1];
            uint32_t ll = (gw > 0)       ? Ds[rd][w]     : 0xFFFFFFFFu;
            uint32_t rr = (gw < WPR - 1) ? Ds[rd][w + 2] : 0xFFFFFFFFu;
            acc &= hshift5_and(cc, ll, rr);
        }
        float* o = out + (size_t)gy * IMG + gw * 32;
#pragma unroll
        for (int k = 0; k < 8; ++k) {
            float4 v;
            v.x = (acc & (1u << (4 * k + 0))) ? 1.0f : 0.0f;
            v.y = (acc & (1u << (4 * k + 1))) ? 1.0f : 0.0f;
            v.z = (acc & (1u << (4 * k + 2))) ? 1.0f : 0.0f;
            v.w = (acc & (1u << (4 * k + 3))) ? 1.0f : 0.0f;
            *reinterpret_cast<float4*>(o + 4 * k) = v;
        }
    }
}

extern "C" void kernel_launch(void* const* d_in, const int* in_sizes, int n_in,
                              void* d_out, int out_size, void* d_ws, size_t ws_size,
                              hipStream_t stream) {
    const float* x = (const float*)d_in[0];
    float* out = (float*)d_out;
    uint8_t* ws = (uint8_t*)d_ws;

    float*    ths  = (float*)(ws + OFF_THS);
    uint16_t* priv = (uint16_t*)(ws + OFF_PRIV);

    k_hist    <<<NPATCH * NSLICE, 256, 0, stream>>>(x, priv);
    k_scan    <<<NPATCH,          256, 0, stream>>>(priv, ths);
    k_binclose<<<GR * GC,         256, 0, stream>>>(x, ths, out);
}